// Round 7
// baseline (230.278 us; speedup 1.0000x reference)
//
#include <hip/hip_runtime.h>
#include <stdint.h>

// Shapes (fixed by the reference)
#define B_ 8
#define N_ 1024
#define D_ 512
#define H_ 8
#define DH_ 64

// Round 7: k_attn latency/locality fix.
//  - XCD swizzle: 1D grid, bh = bid & 63 -> all 32 blocks of a bh slice land
//    on XCD bid%8 = bh%8; slice (128 KB) fetched from HBM once per XCD.
//  - wave = (iG, jH): i-tile 32, j-half 512 per wave -> grid 2048, per-wave
//    chain 16 steps; partial acc pairs combined via LDS once at the end.
//  - register double-buffer of B-frags (load k+1 before MFMAs of k);
//    adjacency word loaded per-step (L1); no in-loop barriers (spill-safe).

using bf16x8 = __attribute__((ext_vector_type(8))) __bf16;
using f32x4  = __attribute__((ext_vector_type(4))) float;

__device__ __forceinline__ float bf2f(uint32_t u) {
  union { uint32_t u; float f; } c; c.u = u << 16; return c.f;
}
__device__ __forceinline__ uint16_t f2bf(float f) {  // RNE
  union { float f; uint32_t u; } c; c.f = f;
  return (uint16_t)((c.u + 0x7FFFu + ((c.u >> 16) & 1u)) >> 16);
}
__device__ __forceinline__ void load8f(const void* p, size_t idx, int f32, float v[8]) {
  if (f32) {
    const float4* q = (const float4*)((const float*)p + idx);
    float4 a = q[0], b = q[1];
    v[0]=a.x; v[1]=a.y; v[2]=a.z; v[3]=a.w; v[4]=b.x; v[5]=b.y; v[6]=b.z; v[7]=b.w;
  } else {
    uint4 u = *(const uint4*)((const uint16_t*)p + idx);
    const uint32_t* w = (const uint32_t*)&u;
#pragma unroll
    for (int e = 0; e < 4; e++) { v[2*e] = bf2f(w[e] & 0xffffu); v[2*e+1] = bf2f(w[e] >> 16); }
  }
}
__device__ __forceinline__ float load1f(const void* p, size_t idx, int f32) {
  return f32 ? ((const float*)p)[idx] : bf2f(((const uint16_t*)p)[idx]);
}

// block-local dtype detect: scan first 1024 uint16 of x; bf16 N(0,1) never
// has bf16-exponent >= 0x90 (|v|>=2^17); fp32-as-u16 halves are ~uniform.
__device__ __forceinline__ int detect_f32_block(const uint16_t* x, int t, int* sflag) {
  if (t == 0) *sflag = 0;
  __syncthreads();
  uint2 u = ((const uint2*)x)[t];
  uint32_t bad = 0;
  bad |= (((u.x >> 7)  & 0xffu) >= 0x90u);
  bad |= (((u.x >> 23) & 0xffu) >= 0x90u);
  bad |= (((u.y >> 7)  & 0xffu) >= 0x90u);
  bad |= (((u.y >> 23) & 0xffu) >= 0x90u);
  if (__any(bad)) { if ((t & 63) == 0) atomicOr(sflag, 1); }
  __syncthreads();
  return *sflag;
}

// ---------------- k_pp: adj pack (0..2047) | detect->flag (2048) |
//                  LN1 (2049..4096) | W transpose (4097..4160)
__global__ __launch_bounds__(256) void k_pp(const int* __restrict__ adj,
                                            unsigned long long* __restrict__ adjp,
                                            const uint16_t* __restrict__ xr,
                                            int* __restrict__ flag,
                                            const void* __restrict__ x,
                                            const void* __restrict__ g,
                                            const void* __restrict__ bb,
                                            uint16_t* __restrict__ xn,
                                            const void* __restrict__ W,
                                            uint16_t* __restrict__ Wt) {
  const int bx = blockIdx.x, t = threadIdx.x;
  if (bx < 2048) {  // adjacency bit-pack
    const int row  = bx * 4 + (t >> 6);
    const int lane = t & 63;
    const int* ar = adj + (size_t)row * N_;
#pragma unroll
    for (int c = 0; c < 16; c++) {
      unsigned long long m = __ballot(ar[c * 64 + lane] > 0);
      if (lane == 0) adjp[(size_t)row * 16 + c] = m;
    }
    return;
  }
  __shared__ int sflag;
  if (bx == 2048) {  // global flag for k_gemm / k_final
    int f32 = detect_f32_block(xr, t, &sflag);
    if (t == 0) *flag = f32;
    return;
  }
  if (bx >= 4097) {  // W [H][D][DH] -> Wt [H][DH][D] bf16
    const int f32 = detect_f32_block(xr, t, &sflag);
    const int bw = bx - 4097;
    const int h = bw >> 3, dt = bw & 7;
    __shared__ uint16_t tile[64][65];
    const size_t sbase = ((size_t)h * D_ + dt * 64) * DH_;
    for (int e = t; e < 4096; e += 256) tile[e >> 6][e & 63] = f2bf(load1f(W, sbase + e, f32));
    __syncthreads();
    uint16_t* dst = Wt + (size_t)h * DH_ * D_ + dt * 64;
    for (int e = t; e < 4096; e += 256) {
      const int k = e >> 6, dd = e & 63;
      dst[(size_t)k * D_ + dd] = tile[dd][k];
    }
    return;
  }
  // LayerNorm1
  const int f32 = detect_f32_block(xr, t, &sflag);
  const int row  = (bx - 2049) * 4 + (t >> 6);
  const int lane = t & 63;
  const size_t base = (size_t)row * D_ + lane * 8;
  float v[8]; load8f(x, base, f32, v);
  float s = 0.f, sq = 0.f;
#pragma unroll
  for (int e = 0; e < 8; e++) { s += v[e]; sq += v[e] * v[e]; }
#pragma unroll
  for (int d = 32; d; d >>= 1) { s += __shfl_xor(s, d); sq += __shfl_xor(sq, d); }
  const float mean = s * (1.0f / D_);
  float var = fmaxf(sq * (1.0f / D_) - mean * mean, 0.0f);
  const float inv = 1.0f / (sqrtf(var) + 1e-6f);
  float gv[8], bv[8];
  load8f(g, lane * 8, f32, gv); load8f(bb, lane * 8, f32, bv);
  uint4 ov; uint32_t* ow = (uint32_t*)&ov;
#pragma unroll
  for (int e = 0; e < 4; e++) {
    float o0 = gv[2*e]   * ((v[2*e]   - mean) * inv) + bv[2*e];
    float o1 = gv[2*e+1] * ((v[2*e+1] - mean) * inv) + bv[2*e+1];
    ow[e] = (uint32_t)f2bf(o0) | ((uint32_t)f2bf(o1) << 16);
  }
  *(uint4*)(xn + base) = ov;
}

// ---------------- h = xn @ W per head -> ht[bh][dh][n] bf16, + fs/fd epilogue
__global__ __launch_bounds__(256, 2) void k_gemm(const uint16_t* __restrict__ xn,
                                              const uint16_t* __restrict__ Wt,
                                              uint16_t* __restrict__ ht,
                                              const void* __restrict__ asr,
                                              const void* __restrict__ adst,
                                              float* __restrict__ fs,
                                              float* __restrict__ fd,
                                              const int* __restrict__ flag) {
  const int h = blockIdx.x;
  const int r0 = blockIdx.y * 64;
  const int t = threadIdx.x;
  const int wv = t >> 6, lane = t & 63, q = lane >> 4, m16 = lane & 15;
  const int wr = wv >> 1, wc = wv & 1;

  __shared__ union {
    struct { __align__(16) uint16_t A[64 * 40]; __align__(16) uint16_t Bt[64 * 40]; } st;
    __align__(16) uint16_t tr[64 * 72];  // [dh][seq] transpose buffer
  } L;

  f32x4 acc[2][2] = {};
  const int srow = t >> 2, soff = (t & 3) * 8;
  const uint16_t* gA = xn + (size_t)(r0 + srow) * D_ + soff;
  const uint16_t* gB = Wt + ((size_t)h * DH_ + srow) * D_ + soff;
  uint16_t* lA = &L.st.A[srow * 40 + soff];
  uint16_t* lB = &L.st.Bt[srow * 40 + soff];

  for (int k0 = 0; k0 < D_; k0 += 32) {
    uint4 va = *(const uint4*)(gA + k0);
    uint4 vb = *(const uint4*)(gB + k0);
    __syncthreads();               // WAR
    *(uint4*)lA = va;
    *(uint4*)lB = vb;
    __syncthreads();               // RAW
    bf16x8 a0 = *(const bf16x8*)&L.st.A[(wr * 32 + m16) * 40 + q * 8];
    bf16x8 a1 = *(const bf16x8*)&L.st.A[(wr * 32 + 16 + m16) * 40 + q * 8];
    bf16x8 b0 = *(const bf16x8*)&L.st.Bt[(wc * 32 + m16) * 40 + q * 8];
    bf16x8 b1 = *(const bf16x8*)&L.st.Bt[(wc * 32 + 16 + m16) * 40 + q * 8];
    acc[0][0] = __builtin_amdgcn_mfma_f32_16x16x32_bf16(a0, b0, acc[0][0], 0, 0, 0);
    acc[0][1] = __builtin_amdgcn_mfma_f32_16x16x32_bf16(a0, b1, acc[0][1], 0, 0, 0);
    acc[1][0] = __builtin_amdgcn_mfma_f32_16x16x32_bf16(a1, b0, acc[1][0], 0, 0, 0);
    acc[1][1] = __builtin_amdgcn_mfma_f32_16x16x32_bf16(a1, b1, acc[1][1], 0, 0, 0);
  }
  __syncthreads();
#pragma unroll
  for (int i2 = 0; i2 < 2; i2++)
#pragma unroll
    for (int j2 = 0; j2 < 2; j2++) {
      f32x4 vv = acc[i2][j2];
      const int sl = wr * 32 + i2 * 16 + q * 4;   // seq-local
      const int kl = wc * 32 + j2 * 16 + m16;     // dh-local
#pragma unroll
      for (int r = 0; r < 4; r++) L.tr[kl * 72 + sl + r] = f2bf(vv[r]);
    }
  __syncthreads();
  const int b = r0 >> 10, n0 = r0 & 1023;
  {
    const int k = t >> 2, ns = (t & 3) * 16;
    const size_t base = (((size_t)b * H_ + h) * DH_ + k) * (size_t)N_ + n0 + ns;
    *(uint4*)(ht + base) = *(const uint4*)&L.tr[k * 72 + ns];
    *(uint4*)(ht + base + 8) = *(const uint4*)&L.tr[k * 72 + ns + 8];
  }
  {  // fused fs/fd: fs[bh][n] = sum_dh h[n][dh]*a_src[h][dh]
    const int f32 = *flag;
    const int nl = t >> 2, qd = (t & 3) * 16;
    float ss = 0.f, sd = 0.f;
#pragma unroll
    for (int dd = 0; dd < 16; dd++) {
      float hv = bf2f(L.tr[(qd + dd) * 72 + nl]);
      ss = fmaf(hv, load1f(asr,  h * DH_ + qd + dd, f32), ss);
      sd = fmaf(hv, load1f(adst, h * DH_ + qd + dd, f32), sd);
    }
    ss += __shfl_xor(ss, 1); ss += __shfl_xor(ss, 2);
    sd += __shfl_xor(sd, 1); sd += __shfl_xor(sd, 2);
    if ((t & 3) == 0) {
      fs[((size_t)b * H_ + h) * N_ + n0 + nl] = ss;
      fd[((size_t)b * H_ + h) * N_ + n0 + nl] = sd;
    }
  }
}

// ---------------- attention: out[i,dh] = (1/l_i) sum_j p_ij h[j,dh]
// p_ij = adj_ij * max(Es_i*Ed_j, Es2_i*Ed2_j); B-frags direct from global.
// grid 2048 1D: bh = bid&63 (XCD = bh%8), it = bid>>6 (32-i tile).
// wave wv: iG = wv&1 (16-i group), jH = wv>>1 (512-j half). Partial-acc
// pairs combined via LDS with ONE epilogue barrier.
__global__ __launch_bounds__(256, 2) void k_attn(const uint16_t* __restrict__ ht,
                                                 const float* __restrict__ fs,
                                                 const float* __restrict__ fd,
                                                 const uint32_t* __restrict__ adjp,
                                                 uint16_t* __restrict__ oat) {
  const int bid = blockIdx.x;
  const int bh = bid & 63, it = bid >> 6;
  const int b = bh >> 3, h = bh & 7;
  const int i0 = it * 32;
  const int t = threadIdx.x, wv = t >> 6, lane = t & 63, q = lane >> 4, m16 = lane & 15;
  const int iG = wv & 1, jH = wv >> 1;
  __shared__ __align__(16) float2 Edi[N_];       // (e^{fd_j}, e^{0.2 fd_j}) 8 KB
  __shared__ __align__(16) f32x4 Red[2][64][5];  // partial accs, 10 KB
  for (int j = t; j < N_; j += 256) {
    float fdv = fd[(size_t)bh * N_ + j];
    Edi[j] = make_float2(exp2f(fdv * 1.44269504f), exp2f(fdv * 0.28853901f));
  }
  const int iA = i0 + iG * 16 + m16;
  const float fsv = fs[(size_t)bh * N_ + iA];
  const float Es  = exp2f(fsv * 1.44269504f);
  const float Es2 = exp2f(fsv * 0.28853901f);
  const uint32_t* arow = adjp + ((size_t)b * N_ + iA) * 32 + jH * 16;
  const uint16_t* gB = ht + (size_t)bh * (DH_ * N_) + (size_t)m16 * N_ + jH * 512 + q * 8;
  union { uint16_t u[8]; bf16x8 v; } ones;
#pragma unroll
  for (int e = 0; e < 8; e++) ones.u[e] = 0x3F80u;  // 1.0 bf16
  f32x4 acc[5] = {};
  __syncthreads();  // Edi ready
  // preload step-0 B-frags
  bf16x8 c0 = *(const bf16x8*)(gB);
  bf16x8 c1 = *(const bf16x8*)(gB + 16 * N_);
  bf16x8 c2 = *(const bf16x8*)(gB + 32 * N_);
  bf16x8 c3 = *(const bf16x8*)(gB + 48 * N_);
  for (int k = 0; k < 16; k++) {
    const int jn = ((k + 1) & 15) * 32;           // wraps; step-15 prefetch unused
    bf16x8 n0 = *(const bf16x8*)(gB + jn);
    bf16x8 n1 = *(const bf16x8*)(gB + 16 * N_ + jn);
    bf16x8 n2 = *(const bf16x8*)(gB + 32 * N_ + jn);
    bf16x8 n3 = *(const bf16x8*)(gB + 48 * N_ + jn);
    const uint32_t aword = arow[k];
    const uint32_t abyte = (aword >> (q * 8)) & 0xffu;
    const float2* ed = &Edi[jH * 512 + k * 32 + q * 8];
    float4 e0 = *(const float4*)(ed);
    float4 e1 = *(const float4*)(ed + 2);
    float4 e2 = *(const float4*)(ed + 4);
    float4 e3 = *(const float4*)(ed + 6);
    float pm[8];
    pm[0] = fmaxf(Es * e0.x, Es2 * e0.y);
    pm[1] = fmaxf(Es * e0.z, Es2 * e0.w);
    pm[2] = fmaxf(Es * e1.x, Es2 * e1.y);
    pm[3] = fmaxf(Es * e1.z, Es2 * e1.w);
    pm[4] = fmaxf(Es * e2.x, Es2 * e2.y);
    pm[5] = fmaxf(Es * e2.z, Es2 * e2.w);
    pm[6] = fmaxf(Es * e3.x, Es2 * e3.y);
    pm[7] = fmaxf(Es * e3.z, Es2 * e3.w);
    union { __bf16 bv[8]; bf16x8 v; } af;
#pragma unroll
    for (int e = 0; e < 8; e++) {
      uint32_t msk = (uint32_t)(((int32_t)(abyte << (31 - e))) >> 31);
      af.bv[e] = (__bf16)__uint_as_float(__float_as_uint(pm[e]) & msk);
    }
    acc[0] = __builtin_amdgcn_mfma_f32_16x16x32_bf16(af.v, c0, acc[0], 0, 0, 0);
    acc[1] = __builtin_amdgcn_mfma_f32_16x16x32_bf16(af.v, c1, acc[1], 0, 0, 0);
    acc[2] = __builtin_amdgcn_mfma_f32_16x16x32_bf16(af.v, c2, acc[2], 0, 0, 0);
    acc[3] = __builtin_amdgcn_mfma_f32_16x16x32_bf16(af.v, c3, acc[3], 0, 0, 0);
    acc[4] = __builtin_amdgcn_mfma_f32_16x16x32_bf16(af.v, ones.v, acc[4], 0, 0, 0);
    c0 = n0; c1 = n1; c2 = n2; c3 = n3;
  }
  if (jH == 1) {
#pragma unroll
    for (int nt = 0; nt < 5; nt++) Red[wv - 2][lane][nt] = acc[nt];
  }
  __syncthreads();
  if (jH == 0) {
#pragma unroll
    for (int nt = 0; nt < 5; nt++) {
      f32x4 o = Red[wv][lane][nt];
#pragma unroll
      for (int r = 0; r < 4; r++) acc[nt][r] += o[r];
    }
    float linv[4];
#pragma unroll
    for (int r = 0; r < 4; r++) linv[r] = 1.0f / acc[4][r];
    const int ibl = i0 + iG * 16 + q * 4;
#pragma unroll
    for (int nt = 0; nt < 4; nt++)
#pragma unroll
      for (int r = 0; r < 4; r++) {
        oat[((size_t)b * N_ + ibl + r) * D_ + h * DH_ + nt * 16 + m16] =
            f2bf(acc[nt][r] * linv[r]);
      }
  }
}

// ---------------- final: y = LN2(x + elu(oat)); output dtype matches input
__global__ __launch_bounds__(256) void k_final(const void* __restrict__ x,
                                               const uint16_t* __restrict__ oa,
                                               const void* __restrict__ g,
                                               const void* __restrict__ bb,
                                               void* __restrict__ out,
                                               const int* __restrict__ flag) {
  const int f32 = *flag;
  const int row = blockIdx.x * 4 + (threadIdx.x >> 6);
  const int lane = threadIdx.x & 63;
  const size_t base = (size_t)row * D_ + lane * 8;
  float xv[8]; load8f(x, base, f32, xv);
  uint4 av = *(const uint4*)(oa + base);
  const uint32_t* aw = (const uint32_t*)&av;
  float v[8], s = 0.f, sq = 0.f;
#pragma unroll
  for (int e = 0; e < 4; e++) {
    float a0 = bf2f(aw[e] & 0xffffu), a1 = bf2f(aw[e] >> 16);
    a0 = a0 > 0.f ? a0 : exp2f(a0 * 1.44269504f) - 1.0f;
    a1 = a1 > 0.f ? a1 : exp2f(a1 * 1.44269504f) - 1.0f;
    float t0 = xv[2*e] + a0, t1 = xv[2*e+1] + a1;
    v[2*e] = t0; v[2*e+1] = t1;
    s += t0 + t1; sq += t0 * t0 + t1 * t1;
  }
#pragma unroll
  for (int d = 32; d; d >>= 1) { s += __shfl_xor(s, d); sq += __shfl_xor(sq, d); }
  const float mean = s * (1.0f / D_);
  float var = fmaxf(sq * (1.0f / D_) - mean * mean, 0.0f);
  const float inv = 1.0f / (sqrtf(var) + 1e-6f);
  float gv[8], bv[8];
  load8f(g, lane * 8, f32, gv); load8f(bb, lane * 8, f32, bv);
  float r8[8];
#pragma unroll
  for (int e = 0; e < 8; e++) r8[e] = gv[e] * ((v[e] - mean) * inv) + bv[e];
  if (f32) {
    float* o = (float*)out + base;
    float4 o0 = {r8[0], r8[1], r8[2], r8[3]};
    float4 o1 = {r8[4], r8[5], r8[6], r8[7]};
    *(float4*)(o) = o0;
    *(float4*)(o + 4) = o1;
  } else {
    uint4 ov; uint32_t* ow = (uint32_t*)&ov;
#pragma unroll
    for (int e = 0; e < 4; e++)
      ow[e] = (uint32_t)f2bf(r8[2*e]) | ((uint32_t)f2bf(r8[2*e+1]) << 16);
    *(uint4*)((uint16_t*)out + base) = ov;
  }
}

extern "C" void kernel_launch(void* const* d_in, const int* in_sizes, int n_in,
                              void* d_out, int out_size, void* d_ws, size_t ws_size,
                              hipStream_t stream) {
  const void* x = d_in[0];
  // d_in[1] = mask (unused)
  const int* adj = (const int*)d_in[2];
  const void* W = d_in[3];
  const void* asr = d_in[4];
  const void* adst = d_in[5];
  const void* g1 = d_in[6];
  const void* b1 = d_in[7];
  const void* g2 = d_in[8];
  const void* b2 = d_in[9];

  uint8_t* ws = (uint8_t*)d_ws;
  uint16_t* ht = (uint16_t*)(ws);                // 8 MB  [bh][dh][n] bf16
  uint16_t* xn = (uint16_t*)(ws + 8388608);      // 8 MB  (reused as oat)
  uint16_t* oat = xn;
  uint16_t* Wt = (uint16_t*)(ws + 16777216);     // 512 KB
  uint32_t* adjp = (uint32_t*)(ws + 17301504);   // 1 MB
  float* fs = (float*)(ws + 18350080);           // 256 KB
  float* fd = (float*)(ws + 18612224);           // 256 KB
  int* flag = (int*)(ws + 18874368);             // 4 B dtype flag

  k_pp<<<dim3(4161), dim3(256), 0, stream>>>(adj, (unsigned long long*)adjp,
                                             (const uint16_t*)x, flag,
                                             x, g1, b1, xn, W, Wt);
  k_gemm<<<dim3(8, 128), dim3(256), 0, stream>>>(xn, Wt, ht, asr, adst, fs, fd, flag);
  k_attn<<<dim3(2048), dim3(256), 0, stream>>>(ht, fs, fd, adjp, oat);
  k_final<<<dim3(2048), dim3(256), 0, stream>>>(x, oat, g2, b2, d_out, flag);
}

// Round 8
// 163.977 us; speedup vs baseline: 1.4043x; 1.4043x over previous
//
#include <hip/hip_runtime.h>
#include <stdint.h>

// Shapes (fixed by the reference)
#define B_ 8
#define N_ 1024
#define D_ 512
#define H_ 8
#define DH_ 64

// Round 8:
//  - k_attn v3: LDS-staged H tiles (128-j chunks, stride 136 = 2-way-only
//    bank pattern), 4 waves share each chunk, wave owns 2 i-frags ->
//    20 MFMA + 8 ds_read per barrier pair. R7 lesson: direct global->MFMA
//    loads serialize (compiler minimizes regs); LDS staging is the proven
//    high-utilization shape. XCD swizzle kept (bid&63=bh).
//  - k_gemm: BK=64 (stride 72), barriers 32->16, 8 MFMA/pair.

using bf16x8 = __attribute__((ext_vector_type(8))) __bf16;
using f32x4  = __attribute__((ext_vector_type(4))) float;

__device__ __forceinline__ float bf2f(uint32_t u) {
  union { uint32_t u; float f; } c; c.u = u << 16; return c.f;
}
__device__ __forceinline__ uint16_t f2bf(float f) {  // RNE
  union { float f; uint32_t u; } c; c.f = f;
  return (uint16_t)((c.u + 0x7FFFu + ((c.u >> 16) & 1u)) >> 16);
}
__device__ __forceinline__ void load8f(const void* p, size_t idx, int f32, float v[8]) {
  if (f32) {
    const float4* q = (const float4*)((const float*)p + idx);
    float4 a = q[0], b = q[1];
    v[0]=a.x; v[1]=a.y; v[2]=a.z; v[3]=a.w; v[4]=b.x; v[5]=b.y; v[6]=b.z; v[7]=b.w;
  } else {
    uint4 u = *(const uint4*)((const uint16_t*)p + idx);
    const uint32_t* w = (const uint32_t*)&u;
#pragma unroll
    for (int e = 0; e < 4; e++) { v[2*e] = bf2f(w[e] & 0xffffu); v[2*e+1] = bf2f(w[e] >> 16); }
  }
}
__device__ __forceinline__ float load1f(const void* p, size_t idx, int f32) {
  return f32 ? ((const float*)p)[idx] : bf2f(((const uint16_t*)p)[idx]);
}

__device__ __forceinline__ int detect_f32_block(const uint16_t* x, int t, int* sflag) {
  if (t == 0) *sflag = 0;
  __syncthreads();
  uint2 u = ((const uint2*)x)[t];
  uint32_t bad = 0;
  bad |= (((u.x >> 7)  & 0xffu) >= 0x90u);
  bad |= (((u.x >> 23) & 0xffu) >= 0x90u);
  bad |= (((u.y >> 7)  & 0xffu) >= 0x90u);
  bad |= (((u.y >> 23) & 0xffu) >= 0x90u);
  if (__any(bad)) { if ((t & 63) == 0) atomicOr(sflag, 1); }
  __syncthreads();
  return *sflag;
}

// ---------------- k_pp: adj pack (0..2047) | detect->flag (2048) |
//                  LN1 (2049..4096) | W transpose (4097..4160)
__global__ __launch_bounds__(256) void k_pp(const int* __restrict__ adj,
                                            unsigned long long* __restrict__ adjp,
                                            const uint16_t* __restrict__ xr,
                                            int* __restrict__ flag,
                                            const void* __restrict__ x,
                                            const void* __restrict__ g,
                                            const void* __restrict__ bb,
                                            uint16_t* __restrict__ xn,
                                            const void* __restrict__ W,
                                            uint16_t* __restrict__ Wt) {
  const int bx = blockIdx.x, t = threadIdx.x;
  if (bx < 2048) {  // adjacency bit-pack
    const int row  = bx * 4 + (t >> 6);
    const int lane = t & 63;
    const int* ar = adj + (size_t)row * N_;
#pragma unroll
    for (int c = 0; c < 16; c++) {
      unsigned long long m = __ballot(ar[c * 64 + lane] > 0);
      if (lane == 0) adjp[(size_t)row * 16 + c] = m;
    }
    return;
  }
  __shared__ int sflag;
  if (bx == 2048) {
    int f32 = detect_f32_block(xr, t, &sflag);
    if (t == 0) *flag = f32;
    return;
  }
  if (bx >= 4097) {  // W [H][D][DH] -> Wt [H][DH][D] bf16
    const int f32 = detect_f32_block(xr, t, &sflag);
    const int bw = bx - 4097;
    const int h = bw >> 3, dt = bw & 7;
    __shared__ uint16_t tile[64][65];
    const size_t sbase = ((size_t)h * D_ + dt * 64) * DH_;
    for (int e = t; e < 4096; e += 256) tile[e >> 6][e & 63] = f2bf(load1f(W, sbase + e, f32));
    __syncthreads();
    uint16_t* dst = Wt + (size_t)h * DH_ * D_ + dt * 64;
    for (int e = t; e < 4096; e += 256) {
      const int k = e >> 6, dd = e & 63;
      dst[(size_t)k * D_ + dd] = tile[dd][k];
    }
    return;
  }
  // LayerNorm1
  const int f32 = detect_f32_block(xr, t, &sflag);
  const int row  = (bx - 2049) * 4 + (t >> 6);
  const int lane = t & 63;
  const size_t base = (size_t)row * D_ + lane * 8;
  float v[8]; load8f(x, base, f32, v);
  float s = 0.f, sq = 0.f;
#pragma unroll
  for (int e = 0; e < 8; e++) { s += v[e]; sq += v[e] * v[e]; }
#pragma unroll
  for (int d = 32; d; d >>= 1) { s += __shfl_xor(s, d); sq += __shfl_xor(sq, d); }
  const float mean = s * (1.0f / D_);
  float var = fmaxf(sq * (1.0f / D_) - mean * mean, 0.0f);
  const float inv = 1.0f / (sqrtf(var) + 1e-6f);
  float gv[8], bv[8];
  load8f(g, lane * 8, f32, gv); load8f(bb, lane * 8, f32, bv);
  uint4 ov; uint32_t* ow = (uint32_t*)&ov;
#pragma unroll
  for (int e = 0; e < 4; e++) {
    float o0 = gv[2*e]   * ((v[2*e]   - mean) * inv) + bv[2*e];
    float o1 = gv[2*e+1] * ((v[2*e+1] - mean) * inv) + bv[2*e+1];
    ow[e] = (uint32_t)f2bf(o0) | ((uint32_t)f2bf(o1) << 16);
  }
  *(uint4*)(xn + base) = ov;
}

// ---------------- h = xn @ W per head -> ht[bh][dh][n] bf16, + fs/fd epilogue
// BK=64: 8 K-iters, 16 barriers, 8 MFMA per barrier-pair per wave.
__global__ __launch_bounds__(256, 2) void k_gemm(const uint16_t* __restrict__ xn,
                                              const uint16_t* __restrict__ Wt,
                                              uint16_t* __restrict__ ht,
                                              const void* __restrict__ asr,
                                              const void* __restrict__ adst,
                                              float* __restrict__ fs,
                                              float* __restrict__ fd,
                                              const int* __restrict__ flag) {
  const int h = blockIdx.x;
  const int r0 = blockIdx.y * 64;
  const int t = threadIdx.x;
  const int wv = t >> 6, lane = t & 63, q = lane >> 4, m16 = lane & 15;
  const int wr = wv >> 1, wc = wv & 1;

  __shared__ union {
    struct { __align__(16) uint16_t A[64 * 72]; __align__(16) uint16_t Bt[64 * 72]; } st;
    __align__(16) uint16_t tr[64 * 72];  // [dh][seq] transpose buffer
  } L;

  f32x4 acc[2][2] = {};
  const int srow = t >> 2, soff = (t & 3) * 16;
  const uint16_t* gA = xn + (size_t)(r0 + srow) * D_ + soff;
  const uint16_t* gB = Wt + ((size_t)h * DH_ + srow) * D_ + soff;
  uint16_t* lA = &L.st.A[srow * 72 + soff];
  uint16_t* lB = &L.st.Bt[srow * 72 + soff];

  for (int k0 = 0; k0 < D_; k0 += 64) {
    uint4 va0 = *(const uint4*)(gA + k0);
    uint4 va1 = *(const uint4*)(gA + k0 + 8);
    uint4 vb0 = *(const uint4*)(gB + k0);
    uint4 vb1 = *(const uint4*)(gB + k0 + 8);
    __syncthreads();               // WAR
    *(uint4*)lA = va0;  *(uint4*)(lA + 8) = va1;
    *(uint4*)lB = vb0;  *(uint4*)(lB + 8) = vb1;
    __syncthreads();               // RAW
#pragma unroll
    for (int ks = 0; ks < 2; ks++) {
      bf16x8 a0 = *(const bf16x8*)&L.st.A[(wr * 32 + m16) * 72 + ks * 32 + q * 8];
      bf16x8 a1 = *(const bf16x8*)&L.st.A[(wr * 32 + 16 + m16) * 72 + ks * 32 + q * 8];
      bf16x8 b0 = *(const bf16x8*)&L.st.Bt[(wc * 32 + m16) * 72 + ks * 32 + q * 8];
      bf16x8 b1 = *(const bf16x8*)&L.st.Bt[(wc * 32 + 16 + m16) * 72 + ks * 32 + q * 8];
      acc[0][0] = __builtin_amdgcn_mfma_f32_16x16x32_bf16(a0, b0, acc[0][0], 0, 0, 0);
      acc[0][1] = __builtin_amdgcn_mfma_f32_16x16x32_bf16(a0, b1, acc[0][1], 0, 0, 0);
      acc[1][0] = __builtin_amdgcn_mfma_f32_16x16x32_bf16(a1, b0, acc[1][0], 0, 0, 0);
      acc[1][1] = __builtin_amdgcn_mfma_f32_16x16x32_bf16(a1, b1, acc[1][1], 0, 0, 0);
    }
  }
  __syncthreads();
#pragma unroll
  for (int i2 = 0; i2 < 2; i2++)
#pragma unroll
    for (int j2 = 0; j2 < 2; j2++) {
      f32x4 vv = acc[i2][j2];
      const int sl = wr * 32 + i2 * 16 + q * 4;   // seq-local
      const int kl = wc * 32 + j2 * 16 + m16;     // dh-local
#pragma unroll
      for (int r = 0; r < 4; r++) L.tr[kl * 72 + sl + r] = f2bf(vv[r]);
    }
  __syncthreads();
  const int b = r0 >> 10, n0 = r0 & 1023;
  {
    const int k = t >> 2, ns = (t & 3) * 16;
    const size_t base = (((size_t)b * H_ + h) * DH_ + k) * (size_t)N_ + n0 + ns;
    *(uint4*)(ht + base) = *(const uint4*)&L.tr[k * 72 + ns];
    *(uint4*)(ht + base + 8) = *(const uint4*)&L.tr[k * 72 + ns + 8];
  }
  {  // fused fs/fd
    const int f32 = *flag;
    const int nl = t >> 2, qd = (t & 3) * 16;
    float ss = 0.f, sd = 0.f;
#pragma unroll
    for (int dd = 0; dd < 16; dd++) {
      float hv = bf2f(L.tr[(qd + dd) * 72 + nl]);
      ss = fmaf(hv, load1f(asr,  h * DH_ + qd + dd, f32), ss);
      sd = fmaf(hv, load1f(adst, h * DH_ + qd + dd, f32), sd);
    }
    ss += __shfl_xor(ss, 1); ss += __shfl_xor(ss, 2);
    sd += __shfl_xor(sd, 1); sd += __shfl_xor(sd, 2);
    if ((t & 3) == 0) {
      fs[((size_t)b * H_ + h) * N_ + n0 + nl] = ss;
      fd[((size_t)b * H_ + h) * N_ + n0 + nl] = sd;
    }
  }
}

// ---------------- attention v3: out[i,dh] = (1/l_i) sum_j p_ij h[j,dh]
// grid 512: bh = bid&63 (XCD = bh%8), itile = bid>>6 (128-i tile).
// LDS-staged H in 128-j chunks (stride 136); wave owns 2 i-frags of 16.
// p_ij = adj_ij * max(Es_i*Ed_j, Es2_i*Ed2_j); l_i via ones-row MFMA.
__global__ __launch_bounds__(256, 2) void k_attn(const uint16_t* __restrict__ ht,
                                                 const float* __restrict__ fs,
                                                 const float* __restrict__ fd,
                                                 const uint32_t* __restrict__ adjp,
                                                 uint16_t* __restrict__ oat) {
  const int bid = blockIdx.x;
  const int bh = bid & 63, itile = bid >> 6;
  const int b = bh >> 3, h = bh & 7;
  const int i0 = itile * 128;
  const int t = threadIdx.x, wv = t >> 6, lane = t & 63, q = lane >> 4, m16 = lane & 15;
  __shared__ __align__(16) uint16_t Hs[64 * 136];  // 17 KB, stride 136 (2-way only)
  __shared__ __align__(16) float2 Edi[N_];         // 8 KB: (e^{fd_j}, e^{0.2 fd_j})
  for (int j = t; j < N_; j += 256) {
    float fdv = fd[(size_t)bh * N_ + j];
    Edi[j] = make_float2(exp2f(fdv * 1.44269504f), exp2f(fdv * 0.28853901f));
  }
  const int iA0 = i0 + wv * 32 + m16;
  const int iA1 = iA0 + 16;
  const float fs0 = fs[(size_t)bh * N_ + iA0];
  const float fs1 = fs[(size_t)bh * N_ + iA1];
  const float Es0  = exp2f(fs0 * 1.44269504f), Es20 = exp2f(fs0 * 0.28853901f);
  const float Es1  = exp2f(fs1 * 1.44269504f), Es21 = exp2f(fs1 * 0.28853901f);
  const uint32_t* arow0 = adjp + ((size_t)b * N_ + iA0) * 32;
  const uint32_t* arow1 = adjp + ((size_t)b * N_ + iA1) * 32;
  const uint16_t* gH = ht + (size_t)bh * (DH_ * N_) + (size_t)(t >> 2) * N_ + (t & 3) * 32;
  uint16_t* lH = &Hs[(t >> 2) * 136 + (t & 3) * 32];
  union { uint16_t u[8]; bf16x8 v; } ones;
#pragma unroll
  for (int e = 0; e < 8; e++) ones.u[e] = 0x3F80u;  // 1.0 bf16
  f32x4 acc[2][5] = {};
  __syncthreads();  // Edi ready
  for (int c = 0; c < 8; c++) {
    const int jc = c * 128;
    uint4 v0 = *(const uint4*)(gH + jc);
    uint4 v1 = *(const uint4*)(gH + jc + 8);
    uint4 v2 = *(const uint4*)(gH + jc + 16);
    uint4 v3 = *(const uint4*)(gH + jc + 24);
    uint4 aw0 = *(const uint4*)(arow0 + c * 4);   // 4 j-words for frag0
    uint4 aw1 = *(const uint4*)(arow1 + c * 4);
    __syncthreads();               // WAR: prev chunk's reads done
    *(uint4*)(lH)      = v0;
    *(uint4*)(lH + 8)  = v1;
    *(uint4*)(lH + 16) = v2;
    *(uint4*)(lH + 24) = v3;
    __syncthreads();               // RAW
    const uint32_t w0[4] = {aw0.x, aw0.y, aw0.z, aw0.w};
    const uint32_t w1[4] = {aw1.x, aw1.y, aw1.z, aw1.w};
#pragma unroll
    for (int s = 0; s < 4; s++) {
      const int js = s * 32;
      // shared per-step reads
      bf16x8 bf0 = *(const bf16x8*)&Hs[(m16)      * 136 + js + q * 8];
      bf16x8 bf1 = *(const bf16x8*)&Hs[(16 + m16) * 136 + js + q * 8];
      bf16x8 bf2 = *(const bf16x8*)&Hs[(32 + m16) * 136 + js + q * 8];
      bf16x8 bf3 = *(const bf16x8*)&Hs[(48 + m16) * 136 + js + q * 8];
      const float2* ed = &Edi[jc + js + q * 8];
      float4 e0 = *(const float4*)(ed);
      float4 e1 = *(const float4*)(ed + 2);
      float4 e2 = *(const float4*)(ed + 4);
      float4 e3 = *(const float4*)(ed + 6);
      const uint32_t ab0 = (w0[s] >> (q * 8)) & 0xffu;
      const uint32_t ab1 = (w1[s] >> (q * 8)) & 0xffu;
#pragma unroll
      for (int f = 0; f < 2; f++) {
        const float Ea  = f ? Es1 : Es0;
        const float Eb  = f ? Es21 : Es20;
        const uint32_t ab = f ? ab1 : ab0;
        float pm[8];
        pm[0] = fmaxf(Ea * e0.x, Eb * e0.y);
        pm[1] = fmaxf(Ea * e0.z, Eb * e0.w);
        pm[2] = fmaxf(Ea * e1.x, Eb * e1.y);
        pm[3] = fmaxf(Ea * e1.z, Eb * e1.w);
        pm[4] = fmaxf(Ea * e2.x, Eb * e2.y);
        pm[5] = fmaxf(Ea * e2.z, Eb * e2.w);
        pm[6] = fmaxf(Ea * e3.x, Eb * e3.y);
        pm[7] = fmaxf(Ea * e3.z, Eb * e3.w);
        union { __bf16 bv[8]; bf16x8 v; } af;
#pragma unroll
        for (int e = 0; e < 8; e++) {
          uint32_t msk = (uint32_t)(((int32_t)(ab << (31 - e))) >> 31);
          af.bv[e] = (__bf16)__uint_as_float(__float_as_uint(pm[e]) & msk);
        }
        acc[f][0] = __builtin_amdgcn_mfma_f32_16x16x32_bf16(af.v, bf0, acc[f][0], 0, 0, 0);
        acc[f][1] = __builtin_amdgcn_mfma_f32_16x16x32_bf16(af.v, bf1, acc[f][1], 0, 0, 0);
        acc[f][2] = __builtin_amdgcn_mfma_f32_16x16x32_bf16(af.v, bf2, acc[f][2], 0, 0, 0);
        acc[f][3] = __builtin_amdgcn_mfma_f32_16x16x32_bf16(af.v, bf3, acc[f][3], 0, 0, 0);
        acc[f][4] = __builtin_amdgcn_mfma_f32_16x16x32_bf16(af.v, ones.v, acc[f][4], 0, 0, 0);
      }
    }
  }
#pragma unroll
  for (int f = 0; f < 2; f++) {
    float linv[4];
#pragma unroll
    for (int r = 0; r < 4; r++) linv[r] = 1.0f / acc[f][4][r];
    const int ibl = i0 + wv * 32 + f * 16 + q * 4;
#pragma unroll
    for (int nt = 0; nt < 4; nt++)
#pragma unroll
      for (int r = 0; r < 4; r++) {
        oat[((size_t)b * N_ + ibl + r) * D_ + h * DH_ + nt * 16 + m16] =
            f2bf(acc[f][nt][r] * linv[r]);
      }
  }
}

// ---------------- final: y = LN2(x + elu(oat)); output dtype matches input
__global__ __launch_bounds__(256) void k_final(const void* __restrict__ x,
                                               const uint16_t* __restrict__ oa,
                                               const void* __restrict__ g,
                                               const void* __restrict__ bb,
                                               void* __restrict__ out,
                                               const int* __restrict__ flag) {
  const int f32 = *flag;
  const int row = blockIdx.x * 4 + (threadIdx.x >> 6);
  const int lane = threadIdx.x & 63;
  const size_t base = (size_t)row * D_ + lane * 8;
  float xv[8]; load8f(x, base, f32, xv);
  uint4 av = *(const uint4*)(oa + base);
  const uint32_t* aw = (const uint32_t*)&av;
  float v[8], s = 0.f, sq = 0.f;
#pragma unroll
  for (int e = 0; e < 4; e++) {
    float a0 = bf2f(aw[e] & 0xffffu), a1 = bf2f(aw[e] >> 16);
    a0 = a0 > 0.f ? a0 : exp2f(a0 * 1.44269504f) - 1.0f;
    a1 = a1 > 0.f ? a1 : exp2f(a1 * 1.44269504f) - 1.0f;
    float t0 = xv[2*e] + a0, t1 = xv[2*e+1] + a1;
    v[2*e] = t0; v[2*e+1] = t1;
    s += t0 + t1; sq += t0 * t0 + t1 * t1;
  }
#pragma unroll
  for (int d = 32; d; d >>= 1) { s += __shfl_xor(s, d); sq += __shfl_xor(sq, d); }
  const float mean = s * (1.0f / D_);
  float var = fmaxf(sq * (1.0f / D_) - mean * mean, 0.0f);
  const float inv = 1.0f / (sqrtf(var) + 1e-6f);
  float gv[8], bv[8];
  load8f(g, lane * 8, f32, gv); load8f(bb, lane * 8, f32, bv);
  float r8[8];
#pragma unroll
  for (int e = 0; e < 8; e++) r8[e] = gv[e] * ((v[e] - mean) * inv) + bv[e];
  if (f32) {
    float* o = (float*)out + base;
    float4 o0 = {r8[0], r8[1], r8[2], r8[3]};
    float4 o1 = {r8[4], r8[5], r8[6], r8[7]};
    *(float4*)(o) = o0;
    *(float4*)(o + 4) = o1;
  } else {
    uint4 ov; uint32_t* ow = (uint32_t*)&ov;
#pragma unroll
    for (int e = 0; e < 4; e++)
      ow[e] = (uint32_t)f2bf(r8[2*e]) | ((uint32_t)f2bf(r8[2*e+1]) << 16);
    *(uint4*)((uint16_t*)out + base) = ov;
  }
}

extern "C" void kernel_launch(void* const* d_in, const int* in_sizes, int n_in,
                              void* d_out, int out_size, void* d_ws, size_t ws_size,
                              hipStream_t stream) {
  const void* x = d_in[0];
  // d_in[1] = mask (unused)
  const int* adj = (const int*)d_in[2];
  const void* W = d_in[3];
  const void* asr = d_in[4];
  const void* adst = d_in[5];
  const void* g1 = d_in[6];
  const void* b1 = d_in[7];
  const void* g2 = d_in[8];
  const void* b2 = d_in[9];

  uint8_t* ws = (uint8_t*)d_ws;
  uint16_t* ht = (uint16_t*)(ws);                // 8 MB  [bh][dh][n] bf16
  uint16_t* xn = (uint16_t*)(ws + 8388608);      // 8 MB  (reused as oat)
  uint16_t* oat = xn;
  uint16_t* Wt = (uint16_t*)(ws + 16777216);     // 512 KB
  uint32_t* adjp = (uint32_t*)(ws + 17301504);   // 1 MB
  float* fs = (float*)(ws + 18350080);           // 256 KB
  float* fd = (float*)(ws + 18612224);           // 256 KB
  int* flag = (int*)(ws + 18874368);             // 4 B dtype flag

  k_pp<<<dim3(4161), dim3(256), 0, stream>>>(adj, (unsigned long long*)adjp,
                                             (const uint16_t*)x, flag,
                                             x, g1, b1, xn, W, Wt);
  k_gemm<<<dim3(8, 128), dim3(256), 0, stream>>>(xn, Wt, ht, asr, adst, fs, fd, flag);
  k_attn<<<dim3(512), dim3(256), 0, stream>>>(ht, fs, fd, adjp, oat);
  k_final<<<dim3(2048), dim3(256), 0, stream>>>(x, oat, g2, b2, d_out, flag);
}